// Round 18
// baseline (44.081 us; speedup 1.0000x reference)
//
#include <hip/hip_runtime.h>
#include <string.h>

#define LOG2E 1.44269504088896340736f
#define LN2   0.69314718055994530942f

typedef _Float16 f16x8 __attribute__((ext_vector_type(8)));
typedef __attribute__((ext_vector_type(2))) float f32x2;
typedef __attribute__((ext_vector_type(16))) float f32x16;

// ws float offsets
#define WS_MUP  0        // 8192 x 8 u32 : 16 f16 mu per row
#define WS_AV1  65536    // 8192 f32
#define WS_P1   73728    // 64 x 8192 f32 partials, pass 1
#define WS_P2   598016   // 64 x 8192 f32 partials, pass 2

__device__ __forceinline__ float fast_exp2(float x) {
#if __has_builtin(__builtin_amdgcn_exp2f)
  return __builtin_amdgcn_exp2f(x);
#else
  return exp2f(x);
#endif
}
__device__ __forceinline__ float fast_log2(float x) {
#if __has_builtin(__builtin_amdgcn_logf)
  return __builtin_amdgcn_logf(x);
#else
  return log2f(x);
#endif
}

__device__ __forceinline__ unsigned int pack2_f16(float a, float b) {
  _Float16 h0 = (_Float16)a;
  _Float16 h1 = (_Float16)b;
  unsigned short u0, u1;
  memcpy(&u0, &h0, 2);
  memcpy(&u1, &h1, 2);
  return (unsigned int)u0 | ((unsigned int)u1 << 16);
}

// C-operand swizzle: av_l[t] = av_raw[(t&96) + 8*((t>>2)&3) + 4*((t>>4)&1) + (t&3)]
__device__ __forceinline__ int av_swz(int t) {
  return (t & 96) + ((t >> 2) & 3) * 8 + ((t >> 4) & 1) * 4 + (t & 3);
}

// Packed-f32 exp-sum: 16 trans exps + 8 v_pk_add_f32.
#define EXPSUM16(d, acc2)                                             \
  {                                                                   \
    f32x2 p0, p1, p2, p3, p4, p5, p6, p7;                             \
    p0[0] = fast_exp2(d[0]);  p0[1] = fast_exp2(d[1]);                \
    p1[0] = fast_exp2(d[2]);  p1[1] = fast_exp2(d[3]);                \
    p2[0] = fast_exp2(d[4]);  p2[1] = fast_exp2(d[5]);                \
    p3[0] = fast_exp2(d[6]);  p3[1] = fast_exp2(d[7]);                \
    p4[0] = fast_exp2(d[8]);  p4[1] = fast_exp2(d[9]);                \
    p5[0] = fast_exp2(d[10]); p5[1] = fast_exp2(d[11]);               \
    p6[0] = fast_exp2(d[12]); p6[1] = fast_exp2(d[13]);               \
    p7[0] = fast_exp2(d[14]); p7[1] = fast_exp2(d[15]);               \
    f32x2 s0 = p0 + p1, s1 = p2 + p3, s2 = p4 + p5, s3 = p6 + p7;     \
    acc2 += (s0 + s1) + (s2 + s3);                                    \
  }

// Shared inner loop: 4 tiles x 4 strips, f16 single-MFMA, swizzled-av C-init.
__device__ __forceinline__ void inner_core(
    const f16x8 b0, const f16x8 b1, const f16x8 b2, const f16x8 b3,
    const unsigned int* __restrict__ tl, const float* __restrict__ av_l,
    float* __restrict__ part, int chunk, int r0, int lr, int hi, int l) {
  f32x2 acc2_0 = {0.f, 0.f}, acc2_1 = {0.f, 0.f};
  f32x2 acc2_2 = {0.f, 0.f}, acc2_3 = {0.f, 0.f};
#pragma unroll
  for (int tile = 0; tile < 4; ++tile) {
    const f16x8 a = *(const f16x8*)(tl + (tile * 32 + lr) * 12 + hi * 4);
    const f32x16 C = *(const f32x16*)(av_l + tile * 32 + hi * 16);
    {
      f32x16 d0 = __builtin_amdgcn_mfma_f32_32x32x16_f16(a, b0, C, 0, 0, 0);
      f32x16 d1 = __builtin_amdgcn_mfma_f32_32x32x16_f16(a, b1, C, 0, 0, 0);
      EXPSUM16(d0, acc2_0)
      EXPSUM16(d1, acc2_1)
    }
    {
      f32x16 d2 = __builtin_amdgcn_mfma_f32_32x32x16_f16(a, b2, C, 0, 0, 0);
      f32x16 d3 = __builtin_amdgcn_mfma_f32_32x32x16_f16(a, b3, C, 0, 0, 0);
      EXPSUM16(d2, acc2_2)
      EXPSUM16(d3, acc2_3)
    }
  }
  float acc0 = acc2_0[0] + acc2_0[1];
  float acc1 = acc2_1[0] + acc2_1[1];
  float acc2 = acc2_2[0] + acc2_2[1];
  float acc3 = acc2_3[0] + acc2_3[1];
  acc0 += __shfl_xor(acc0, 32);
  acc1 += __shfl_xor(acc1, 32);
  acc2 += __shfl_xor(acc2, 32);
  acc3 += __shfl_xor(acc3, 32);
  float* base = part + (size_t)chunk * 8192 + r0 + lr;
  if (l < 32) { base[0]  = acc0; base[64] = acc2; }
  else        { base[32] = acc1; base[96] = acc3; }
}

// Pass 1, TWO chunks per block (grid 32x16): fused prep fills both mu tiles
// (256 threads, one row each); b-fragments loaded once and reused for both
// chunks; sg==0 persists muP + av1.
__global__ __launch_bounds__(256, 4) void k_pass1(
    const float* __restrict__ particles, const float* __restrict__ lw,
    const float* __restrict__ sp,
    const float* __restrict__ A, const float* __restrict__ B,
    unsigned int* __restrict__ muP, float* __restrict__ av1,
    float* __restrict__ part) {
  __shared__ __align__(16) unsigned int tl[2][128 * 12];
  __shared__ __align__(64) float av_l[2][128];
  __shared__ float av_raw[256];
  const int t = threadIdx.x;
  const int bx = blockIdx.x;     // 0..31 -> chunks 2bx, 2bx+1
  const int sg = blockIdx.y;     // 0..15

  // --- fused prep: 256 rows (both chunks), one row per thread ---
  {
    const int j = bx * 256 + t;
    const int h = t >> 7, row = t & 127;
    float x[24];
    {
      const float4* p4 = (const float4*)(particles + (size_t)j * 24);
#pragma unroll
      for (int q = 0; q < 6; ++q) {
        float4 v = p4[q];
        x[q * 4 + 0] = v.x; x[q * 4 + 1] = v.y; x[q * 4 + 2] = v.z; x[q * 4 + 3] = v.w;
      }
    }
    float mrow[16];
    float m2 = 0.f;
#pragma unroll
    for (int k = 0; k < 16; ++k) {
      float s = 0.f;
#pragma unroll
      for (int l2 = 0; l2 < 16; ++l2) s += x[l2] * A[k * 16 + l2];
#pragma unroll
      for (int l2 = 0; l2 < 8; ++l2) s += x[16 + l2] * B[k * 8 + l2];
      mrow[k] = s;
      m2 += s * s;
    }
    unsigned int buf[8];
#pragma unroll
    for (int k = 0; k < 16; k += 2) buf[k >> 1] = pack2_f16(mrow[k], mrow[k + 1]);
    *(uint4*)(tl[h] + row * 12 + 0) = make_uint4(buf[0], buf[1], buf[2], buf[3]);
    *(uint4*)(tl[h] + row * 12 + 4) = make_uint4(buf[4], buf[5], buf[6], buf[7]);
    float av = LOG2E * (lw[j] - 0.5f * m2);
    av_raw[t] = av;
    if (sg == 0) {
      uint4* dst = (uint4*)(muP + (size_t)j * 8);
      dst[0] = make_uint4(buf[0], buf[1], buf[2], buf[3]);
      dst[1] = make_uint4(buf[4], buf[5], buf[6], buf[7]);
      av1[j] = av;
    }
  }
  __syncthreads();
  {
    const int h = t >> 7, tt = t & 127;
    av_l[h][tt] = av_raw[h * 128 + av_swz(tt)];
  }
  __syncthreads();

  const int l = t & 63;
  const int wave = t >> 6;
  const int lr = l & 31;
  const int hi = l >> 5;
  const int r0 = sg * 512 + wave * 128;

  // stationary sp' fragments on the fly, loaded ONCE for both chunks
  f16x8 b[4];
#pragma unroll
  for (int s = 0; s < 4; ++s) {
    const float4* p4 = (const float4*)(sp + (size_t)(r0 + s * 32 + lr) * 16 + hi * 8);
    float4 f0 = p4[0], f1 = p4[1];
    b[s][0] = (_Float16)(LOG2E * f0.x); b[s][1] = (_Float16)(LOG2E * f0.y);
    b[s][2] = (_Float16)(LOG2E * f0.z); b[s][3] = (_Float16)(LOG2E * f0.w);
    b[s][4] = (_Float16)(LOG2E * f1.x); b[s][5] = (_Float16)(LOG2E * f1.y);
    b[s][6] = (_Float16)(LOG2E * f1.z); b[s][7] = (_Float16)(LOG2E * f1.w);
  }

  inner_core(b[0], b[1], b[2], b[3], tl[0], av_l[0], part, bx * 2 + 0, r0, lr, hi, l);
  inner_core(b[0], b[1], b[2], b[3], tl[1], av_l[1], part, bx * 2 + 1, r0, lr, hi, l);
}

// Pass 2, TWO chunks per block: sp' tiles staged on the fly, av2 prologue for
// both chunks, muP b-fragments loaded once.
__global__ __launch_bounds__(256, 4) void k_pass2(
    const float* __restrict__ sp,
    const unsigned int* __restrict__ statv,
    const float* __restrict__ w,
    const float* __restrict__ psrc,
    float* __restrict__ part) {
  __shared__ __align__(16) unsigned int tl[2][128 * 12];
  __shared__ __align__(64) float av_l[2][128];
  __shared__ float sums[256];
  __shared__ float av_raw[256];
  const int t = threadIdx.x;
  const int bx = blockIdx.x;     // 0..31 -> chunks 2bx, 2bx+1
  const int sg = blockIdx.y;     // 0..15

  // stage both sp' tiles: per h, 256 threads cover 128 rows (half-row each)
#pragma unroll
  for (int h = 0; h < 2; ++h) {
    const int row = t >> 1, h2 = t & 1;
    const float4* p4 =
        (const float4*)(sp + (size_t)((bx * 2 + h) * 128 + row) * 16 + h2 * 8);
    float4 f0 = p4[0], f1 = p4[1];
    unsigned int buf[4];
    buf[0] = pack2_f16(LOG2E * f0.x, LOG2E * f0.y);
    buf[1] = pack2_f16(LOG2E * f0.z, LOG2E * f0.w);
    buf[2] = pack2_f16(LOG2E * f1.x, LOG2E * f1.y);
    buf[3] = pack2_f16(LOG2E * f1.z, LOG2E * f1.w);
    *(uint4*)(tl[h] + row * 12 + h2 * 4) = make_uint4(buf[0], buf[1], buf[2], buf[3]);
  }

  // av2 prologue for both chunks
#pragma unroll
  for (int h = 0; h < 2; ++h) {
    const int row = t & 127, half = t >> 7;
    float s = 0.f;
    const float* p = psrc + (size_t)(half * 32) * 8192 + (bx * 2 + h) * 128 + row;
#pragma unroll 8
    for (int c = 0; c < 32; ++c) s += p[(size_t)c * 8192];
    sums[t] = s;
    __syncthreads();
    if (t < 128)
      av_raw[h * 128 + t] = LOG2E * w[(bx * 2 + h) * 128 + t] -
                            fast_log2(sums[t] + sums[t + 128]);
    __syncthreads();
  }
  {
    const int h = t >> 7, tt = t & 127;
    av_l[h][tt] = av_raw[h * 128 + av_swz(tt)];
  }
  __syncthreads();

  const int l = t & 63;
  const int wave = t >> 6;
  const int lr = l & 31;
  const int hi = l >> 5;
  const int r0 = sg * 512 + wave * 128;

  const f16x8 b0 = *(const f16x8*)(statv + (size_t)(r0 + lr) * 8 + hi * 4);
  const f16x8 b1 = *(const f16x8*)(statv + (size_t)(r0 + 32 + lr) * 8 + hi * 4);
  const f16x8 b2 = *(const f16x8*)(statv + (size_t)(r0 + 64 + lr) * 8 + hi * 4);
  const f16x8 b3 = *(const f16x8*)(statv + (size_t)(r0 + 96 + lr) * 8 + hi * 4);

  inner_core(b0, b1, b2, b3, tl[0], av_l[0], part, bx * 2 + 0, r0, lr, hi, l);
  inner_core(b0, b1, b2, b3, tl[1], av_l[1], part, bx * 2 + 1, r0, lr, hi, l);
}

__global__ __launch_bounds__(256) void k_out(
    const float* __restrict__ part, const float* __restrict__ av1,
    float* __restrict__ out) {
  int j = blockIdx.x * 256 + threadIdx.x;
  float s = 0.f;
#pragma unroll
  for (int c = 0; c < 64; ++c) s += part[(size_t)c * 8192 + j];
  out[j] = LN2 * (av1[j] + fast_log2(s));
}

extern "C" void kernel_launch(void* const* d_in, const int* in_sizes, int n_in,
                              void* d_out, int out_size, void* d_ws, size_t ws_size,
                              hipStream_t stream) {
  const float* particles = (const float*)d_in[0];
  const float* lw        = (const float*)d_in[1];
  const float* sp        = (const float*)d_in[2];
  const float* w         = (const float*)d_in[3];
  const float* A         = (const float*)d_in[4];
  const float* B         = (const float*)d_in[5];

  float* ws = (float*)d_ws;
  unsigned int* muP = (unsigned int*)(ws + WS_MUP);
  float* av1  = ws + WS_AV1;
  float* p1   = ws + WS_P1;
  float* p2   = ws + WS_P2;
  float* out  = (float*)d_out;

  // pass 1 (fused prep, 2 chunks/block): tile = mu, stationary = sp'
  k_pass1<<<dim3(32, 16), dim3(256), 0, stream>>>(particles, lw, sp, A, B, muP, av1, p1);
  // pass 2 (2 chunks/block): tile = sp', stationary = mu, av2 in prologue
  k_pass2<<<dim3(32, 16), dim3(256), 0, stream>>>(sp, muP, w, p1, p2);
  k_out<<<dim3(32), dim3(256), 0, stream>>>(p2, av1, out);
}

// Round 19
// 42.067 us; speedup vs baseline: 1.0479x; 1.0479x over previous
//
#include <hip/hip_runtime.h>
#include <string.h>

#define LOG2E 1.44269504088896340736f
#define LN2   0.69314718055994530942f

typedef _Float16 f16x8 __attribute__((ext_vector_type(8)));
typedef __attribute__((ext_vector_type(2))) float f32x2;
typedef __attribute__((ext_vector_type(16))) float f32x16;

// ws float offsets
#define WS_MUP  0        // 8192 x 8 u32 : 16 f16 mu per row
#define WS_AV1  65536    // 8192 f32
#define WS_P1   73728    // 64 x 8192 f32 partials, pass 1
#define WS_P2   598016   // 64 x 8192 f32 partials, pass 2

__device__ __forceinline__ float fast_exp2(float x) {
#if __has_builtin(__builtin_amdgcn_exp2f)
  return __builtin_amdgcn_exp2f(x);
#else
  return exp2f(x);
#endif
}
__device__ __forceinline__ float fast_log2(float x) {
#if __has_builtin(__builtin_amdgcn_logf)
  return __builtin_amdgcn_logf(x);
#else
  return log2f(x);
#endif
}

__device__ __forceinline__ unsigned int pack2_f16(float a, float b) {
  _Float16 h0 = (_Float16)a;
  _Float16 h1 = (_Float16)b;
  unsigned short u0, u1;
  memcpy(&u0, &h0, 2);
  memcpy(&u1, &h1, 2);
  return (unsigned int)u0 | ((unsigned int)u1 << 16);
}

// C-operand swizzle: av_l[t] = av_raw[(t&96) + 8*((t>>2)&3) + 4*((t>>4)&1) + (t&3)]
__device__ __forceinline__ int av_swz(int t) {
  return (t & 96) + ((t >> 2) & 3) * 8 + ((t >> 4) & 1) * 4 + (t & 3);
}

// Packed-f32 exp-sum: 16 trans exps + 8 v_pk_add_f32.
#define EXPSUM16(d, acc2)                                             \
  {                                                                   \
    f32x2 p0, p1, p2, p3, p4, p5, p6, p7;                             \
    p0[0] = fast_exp2(d[0]);  p0[1] = fast_exp2(d[1]);                \
    p1[0] = fast_exp2(d[2]);  p1[1] = fast_exp2(d[3]);                \
    p2[0] = fast_exp2(d[4]);  p2[1] = fast_exp2(d[5]);                \
    p3[0] = fast_exp2(d[6]);  p3[1] = fast_exp2(d[7]);                \
    p4[0] = fast_exp2(d[8]);  p4[1] = fast_exp2(d[9]);                \
    p5[0] = fast_exp2(d[10]); p5[1] = fast_exp2(d[11]);               \
    p6[0] = fast_exp2(d[12]); p6[1] = fast_exp2(d[13]);               \
    p7[0] = fast_exp2(d[14]); p7[1] = fast_exp2(d[15]);               \
    f32x2 s0 = p0 + p1, s1 = p2 + p3, s2 = p4 + p5, s3 = p6 + p7;     \
    acc2 += (s0 + s1) + (s2 + s3);                                    \
  }

// Shared inner loop: 4 tiles x 4 strips, f16 single-MFMA, swizzled-av C-init.
__device__ __forceinline__ void inner_core(
    const f16x8 b0, const f16x8 b1, const f16x8 b2, const f16x8 b3,
    const unsigned int* __restrict__ tl, const float* __restrict__ av_l,
    float* __restrict__ part, int chunk, int r0, int lr, int hi, int l) {
  f32x2 acc2_0 = {0.f, 0.f}, acc2_1 = {0.f, 0.f};
  f32x2 acc2_2 = {0.f, 0.f}, acc2_3 = {0.f, 0.f};
#pragma unroll
  for (int tile = 0; tile < 4; ++tile) {
    const f16x8 a = *(const f16x8*)(tl + (tile * 32 + lr) * 12 + hi * 4);
    const f32x16 C = *(const f32x16*)(av_l + tile * 32 + hi * 16);
    {
      f32x16 d0 = __builtin_amdgcn_mfma_f32_32x32x16_f16(a, b0, C, 0, 0, 0);
      f32x16 d1 = __builtin_amdgcn_mfma_f32_32x32x16_f16(a, b1, C, 0, 0, 0);
      EXPSUM16(d0, acc2_0)
      EXPSUM16(d1, acc2_1)
    }
    {
      f32x16 d2 = __builtin_amdgcn_mfma_f32_32x32x16_f16(a, b2, C, 0, 0, 0);
      f32x16 d3 = __builtin_amdgcn_mfma_f32_32x32x16_f16(a, b3, C, 0, 0, 0);
      EXPSUM16(d2, acc2_2)
      EXPSUM16(d3, acc2_3)
    }
  }
  float acc0 = acc2_0[0] + acc2_0[1];
  float acc1 = acc2_1[0] + acc2_1[1];
  float acc2 = acc2_2[0] + acc2_2[1];
  float acc3 = acc2_3[0] + acc2_3[1];
  acc0 += __shfl_xor(acc0, 32);
  acc1 += __shfl_xor(acc1, 32);
  acc2 += __shfl_xor(acc2, 32);
  acc3 += __shfl_xor(acc3, 32);
  float* base = part + (size_t)chunk * 8192 + r0 + lr;
  if (l < 32) { base[0]  = acc0; base[64] = acc2; }
  else        { base[32] = acc1; base[96] = acc3; }
}

// Pass 1 with fused prep: each block computes its 128-row mu tile in-block
// (f16-packed straight into LDS); sg==0 blocks persist muP (for pass 2) and
// av1 (for k_out). Stationary sp' fragments built on the fly from raw sp.
__global__ __launch_bounds__(256, 4) void k_pass1(
    const float* __restrict__ particles, const float* __restrict__ lw,
    const float* __restrict__ sp,
    const float* __restrict__ A, const float* __restrict__ B,
    unsigned int* __restrict__ muP, float* __restrict__ av1,
    float* __restrict__ part) {
  __shared__ __align__(16) unsigned int tl[128 * 12];
  __shared__ __align__(64) float av_l[128];
  __shared__ float av_raw[128];
  const int t = threadIdx.x;
  const int chunk = blockIdx.x;  // 0..63
  const int sg    = blockIdx.y;  // 0..15

  // --- fused prep: mu tile + av_raw (t<128, one full row each) ---
  if (t < 128) {
    const int j = chunk * 128 + t;
    float x[24];
    {
      const float4* p4 = (const float4*)(particles + (size_t)j * 24);
#pragma unroll
      for (int q = 0; q < 6; ++q) {
        float4 v = p4[q];
        x[q * 4 + 0] = v.x; x[q * 4 + 1] = v.y; x[q * 4 + 2] = v.z; x[q * 4 + 3] = v.w;
      }
    }
    float mrow[16];
    float m2 = 0.f;
#pragma unroll
    for (int k = 0; k < 16; ++k) {
      float s = 0.f;
#pragma unroll
      for (int l2 = 0; l2 < 16; ++l2) s += x[l2] * A[k * 16 + l2];
#pragma unroll
      for (int l2 = 0; l2 < 8; ++l2) s += x[16 + l2] * B[k * 8 + l2];
      mrow[k] = s;
      m2 += s * s;
    }
    unsigned int buf[8];
#pragma unroll
    for (int k = 0; k < 16; k += 2) buf[k >> 1] = pack2_f16(mrow[k], mrow[k + 1]);
    *(uint4*)(tl + t * 12 + 0) = make_uint4(buf[0], buf[1], buf[2], buf[3]);
    *(uint4*)(tl + t * 12 + 4) = make_uint4(buf[4], buf[5], buf[6], buf[7]);
    float av = LOG2E * (lw[j] - 0.5f * m2);
    av_raw[t] = av;
    if (sg == 0) {
      uint4* dst = (uint4*)(muP + (size_t)j * 8);
      dst[0] = make_uint4(buf[0], buf[1], buf[2], buf[3]);
      dst[1] = make_uint4(buf[4], buf[5], buf[6], buf[7]);
      av1[j] = av;
    }
  }
  __syncthreads();
  if (t < 128) av_l[t] = av_raw[av_swz(t)];
  __syncthreads();

  const int l = t & 63;
  const int wave = t >> 6;
  const int lr = l & 31;
  const int hi = l >> 5;
  const int r0 = sg * 512 + wave * 128;

  // stationary sp' fragments on the fly (coalesced: wave covers 2KB/strip)
  f16x8 b[4];
#pragma unroll
  for (int s = 0; s < 4; ++s) {
    const float4* p4 = (const float4*)(sp + (size_t)(r0 + s * 32 + lr) * 16 + hi * 8);
    float4 f0 = p4[0], f1 = p4[1];
    b[s][0] = (_Float16)(LOG2E * f0.x); b[s][1] = (_Float16)(LOG2E * f0.y);
    b[s][2] = (_Float16)(LOG2E * f0.z); b[s][3] = (_Float16)(LOG2E * f0.w);
    b[s][4] = (_Float16)(LOG2E * f1.x); b[s][5] = (_Float16)(LOG2E * f1.y);
    b[s][6] = (_Float16)(LOG2E * f1.z); b[s][7] = (_Float16)(LOG2E * f1.w);
  }

  inner_core(b[0], b[1], b[2], b[3], tl, av_l, part, chunk, r0, lr, hi, l);
}

// Pass 2: tile = sp' chunk (on the fly from raw sp), stationary = muP,
// av2 computed in prologue from p1.
__global__ __launch_bounds__(256, 4) void k_pass2(
    const float* __restrict__ sp,
    const unsigned int* __restrict__ statv,
    const float* __restrict__ w,
    const float* __restrict__ psrc,
    float* __restrict__ part) {
  __shared__ __align__(16) unsigned int tl[128 * 12];
  __shared__ __align__(64) float av_l[128];
  __shared__ float sums[256];
  __shared__ float av_raw[128];
  const int t = threadIdx.x;
  const int chunk = blockIdx.x;  // 0..63
  const int sg    = blockIdx.y;  // 0..15

  // stage sp' tile on the fly: 256 threads, half-row each
  {
    const int row = t >> 1, h2 = t & 1;
    const float4* p4 = (const float4*)(sp + (size_t)(chunk * 128 + row) * 16 + h2 * 8);
    float4 f0 = p4[0], f1 = p4[1];
    unsigned int buf[4];
    buf[0] = pack2_f16(LOG2E * f0.x, LOG2E * f0.y);
    buf[1] = pack2_f16(LOG2E * f0.z, LOG2E * f0.w);
    buf[2] = pack2_f16(LOG2E * f1.x, LOG2E * f1.y);
    buf[3] = pack2_f16(LOG2E * f1.z, LOG2E * f1.w);
    *(uint4*)(tl + row * 12 + h2 * 4) = make_uint4(buf[0], buf[1], buf[2], buf[3]);
  }

  // av2 prologue: reduce p1 over 64 chunks
  {
    const int row = t & 127, half = t >> 7;
    float s = 0.f;
    const float* p = psrc + (size_t)(half * 32) * 8192 + chunk * 128 + row;
#pragma unroll 8
    for (int c = 0; c < 32; ++c) s += p[(size_t)c * 8192];
    sums[t] = s;
    __syncthreads();
    if (t < 128)
      av_raw[t] = LOG2E * w[chunk * 128 + t] - fast_log2(sums[t] + sums[t + 128]);
    __syncthreads();
    if (t < 128) av_l[t] = av_raw[av_swz(t)];
  }
  __syncthreads();

  const int l = t & 63;
  const int wave = t >> 6;
  const int lr = l & 31;
  const int hi = l >> 5;
  const int r0 = sg * 512 + wave * 128;

  const f16x8 b0 = *(const f16x8*)(statv + (size_t)(r0 + lr) * 8 + hi * 4);
  const f16x8 b1 = *(const f16x8*)(statv + (size_t)(r0 + 32 + lr) * 8 + hi * 4);
  const f16x8 b2 = *(const f16x8*)(statv + (size_t)(r0 + 64 + lr) * 8 + hi * 4);
  const f16x8 b3 = *(const f16x8*)(statv + (size_t)(r0 + 96 + lr) * 8 + hi * 4);

  inner_core(b0, b1, b2, b3, tl, av_l, part, chunk, r0, lr, hi, l);
}

__global__ __launch_bounds__(256) void k_out(
    const float* __restrict__ part, const float* __restrict__ av1,
    float* __restrict__ out) {
  int j = blockIdx.x * 256 + threadIdx.x;
  float s = 0.f;
#pragma unroll
  for (int c = 0; c < 64; ++c) s += part[(size_t)c * 8192 + j];
  out[j] = LN2 * (av1[j] + fast_log2(s));
}

extern "C" void kernel_launch(void* const* d_in, const int* in_sizes, int n_in,
                              void* d_out, int out_size, void* d_ws, size_t ws_size,
                              hipStream_t stream) {
  const float* particles = (const float*)d_in[0];
  const float* lw        = (const float*)d_in[1];
  const float* sp        = (const float*)d_in[2];
  const float* w         = (const float*)d_in[3];
  const float* A         = (const float*)d_in[4];
  const float* B         = (const float*)d_in[5];

  float* ws = (float*)d_ws;
  unsigned int* muP = (unsigned int*)(ws + WS_MUP);
  float* av1  = ws + WS_AV1;
  float* p1   = ws + WS_P1;
  float* p2   = ws + WS_P2;
  float* out  = (float*)d_out;

  // pass 1 (fused prep): tile = mu chunks, stationary = sp' -> S1 partials per i
  k_pass1<<<dim3(64, 16), dim3(256), 0, stream>>>(particles, lw, sp, A, B, muP, av1, p1);
  // pass 2: tile = sp' chunks (av2 in prologue), stationary = mu -> S2 partials per j
  k_pass2<<<dim3(64, 16), dim3(256), 0, stream>>>(sp, muP, w, p1, p2);
  k_out<<<dim3(32), dim3(256), 0, stream>>>(p2, av1, out);
}